// Round 9
// baseline (442.180 us; speedup 1.0000x reference)
//
#include <hip/hip_runtime.h>

#define BATCH 16
#define CCH 512
#define LEN 4096
#define LPAD 4098

typedef unsigned short u16;
typedef __bf16 bf16x8 __attribute__((ext_vector_type(8)));
typedef float f32x4 __attribute__((ext_vector_type(4)));
typedef u16 u16x8 __attribute__((ext_vector_type(8)));
typedef u16 u16x4 __attribute__((ext_vector_type(4)));

__device__ __forceinline__ u16 f2bf(float f) {
    unsigned u = __float_as_uint(f);
    u = (u + 0x7fffu + ((u >> 16) & 1u)) >> 16;
    return (u16)u;
}
__device__ __forceinline__ float bf2f(u16 v) {
    return __uint_as_float(((unsigned)v) << 16);
}
__device__ __forceinline__ float silu_f(float v) {
    return v / (1.f + __expf(-v));
}
__device__ __forceinline__ void async16(const u16* g, u16* l) {
    __builtin_amdgcn_global_load_lds(
        (const __attribute__((address_space(1))) unsigned int*)g,
        (__attribute__((address_space(3))) unsigned int*)l, 16, 0, 0);
}

#define SBAR() __builtin_amdgcn_sched_barrier(0)
#define HWBAR() { SBAR(); __builtin_amdgcn_s_barrier(); SBAR(); }
#define WAIT_LGKM0() { asm volatile("s_waitcnt lgkmcnt(0)" ::: "memory"); SBAR(); }
#define WAIT_VM(n) { asm volatile("s_waitcnt vmcnt(" #n ")" ::: "memory"); SBAR(); }

// ---------------------------------------------------------------------------
__global__ __launch_bounds__(256)
void absmean_partial(const float* __restrict__ w1, const float* __restrict__ w2,
                     float* __restrict__ part) {
    const int tid = threadIdx.x;
    const int base = blockIdx.x * 3072;
    float s1 = 0.f, s2 = 0.f;
    for (int i = tid; i < 3072; i += 256) {
        s1 += fabsf(w1[base + i]);
        s2 += fabsf(w2[base + i]);
    }
    __shared__ float r1[256], r2[256];
    r1[tid] = s1; r2[tid] = s2;
    __syncthreads();
    for (int off = 128; off > 0; off >>= 1) {
        if (tid < off) { r1[tid] += r1[tid + off]; r2[tid] += r2[tid + off]; }
        __syncthreads();
    }
    if (tid == 0) { part[blockIdx.x] = r1[0]; part[256 + blockIdx.x] = r2[0]; }
}

__global__ __launch_bounds__(256)
void finalize_scale(const float* __restrict__ part, float* __restrict__ sv) {
    const int tid = threadIdx.x;
    __shared__ float r1[256], r2[256];
    r1[tid] = part[tid]; r2[tid] = part[256 + tid];
    __syncthreads();
    for (int off = 128; off > 0; off >>= 1) {
        if (tid < off) { r1[tid] += r1[tid + off]; r2[tid] += r2[tid + off]; }
        __syncthreads();
    }
    if (tid == 0) {
        sv[0] = fmaxf(r1[0] * (1.f / 786432.f), 1e-5f);
        sv[1] = fmaxf(r2[0] * (1.f / 786432.f), 1e-5f);
    }
}

// ---------------------------------------------------------------------------
__global__ __launch_bounds__(256)
void quantize_w(const float* __restrict__ w, const float* __restrict__ sv,
                int sidx, u16* __restrict__ wqt) {
    const int idx = blockIdx.x * 256 + threadIdx.x;
    const float s = sv[sidx];
    float q = rintf(w[idx] / s);
    q = fmaxf(-1.f, fminf(1.f, q));
    const int o   = idx / 1536;
    const int rem = idx - o * 1536;
    const int i   = rem / 3;
    const int k   = rem - i * 3;
    wqt[k * (CCH * CCH) + o * CCH + i] = f2bf(q);
}

__global__ __launch_bounds__(256)
void zero_pads(u16* __restrict__ h, u16* __restrict__ h1) {
    const int idx = blockIdx.x * 256 + threadIdx.x;   // [0, 16384)
    const int b = idx >> 10;
    const int r = (idx >> 9) & 1;
    const int i = idx & 511;
    const size_t off = ((size_t)b * LPAD + (r ? (LPAD - 1) : 0)) * CCH + i;
    h[off] = 0;
    h1[off] = 0;
}

// ---------------------------------------------------------------------------
__global__ __launch_bounds__(256)
void rms_silu_transpose(const float* __restrict__ x, const float* __restrict__ g,
                        u16* __restrict__ h_t) {
    __shared__ u16   xt[CCH][33];
    __shared__ float red[8][32];
    __shared__ float rinv[32];
    const int tid = threadIdx.x;
    const int bb  = blockIdx.x >> 7;
    const int l0  = (blockIdx.x & 127) << 5;

    const size_t xbase = (size_t)bb * CCH * LEN + l0;
    {
        const int i_hi = tid >> 3;
        const int l4   = (tid & 7) << 2;
        #pragma unroll
        for (int it = 0; it < 16; ++it) {
            const int i = it * 32 + i_hi;
            const float4 v = *(const float4*)&x[xbase + (size_t)i * LEN + l4];
            xt[i][l4 + 0] = f2bf(v.x);
            xt[i][l4 + 1] = f2bf(v.y);
            xt[i][l4 + 2] = f2bf(v.z);
            xt[i][l4 + 3] = f2bf(v.w);
        }
    }
    __syncthreads();
    {
        const int l = tid & 31, seg = tid >> 5;
        const int ibeg = seg * 64;
        float ss = 0.f;
        #pragma unroll 8
        for (int i = ibeg; i < ibeg + 64; ++i) {
            const float v = bf2f(xt[i][l]);
            ss += v * v;
        }
        red[seg][l] = ss;
    }
    __syncthreads();
    if (tid < 32) {
        float tot = 0.f;
        #pragma unroll
        for (int k2 = 0; k2 < 8; ++k2) tot += red[k2][tid];
        rinv[tid] = rsqrtf(tot * (1.f / 512.f) + 1e-6f);
    }
    __syncthreads();
    {
        const int l  = tid >> 3;
        const int i0 = (tid & 7) << 6;
        const float ri = rinv[l];
        const size_t ob = ((size_t)bb * LPAD + l0 + l + 1) * CCH + i0;
        for (int ii = 0; ii < 64; ii += 8) {
            u16x8 ov;
            #pragma unroll
            for (int jj = 0; jj < 8; ++jj) {
                const int i = i0 + ii + jj;
                float v = bf2f(xt[i][l]) * ri * g[i];
                ov[jj] = f2bf(silu_f(v));
            }
            *(u16x8*)&h_t[ob + ii] = ov;
        }
    }
}

// ---------------------------------------------------------------------------
// Conv-as-GEMM, A-DIRECT variant.
// A (ternary weights, 1.5MB, L2-hot) is loaded per-fragment straight from
// global into registers (compiler auto-vmcnt, no barrier coupling).
// Only B (activations) is staged in LDS: double-buffered 2 x 32KB, staged
// with gload_lds using R5's PROVEN swizzle (conflict-free, verified 0 in R5/R6).
// Tile 256(o) x 256(l), BK=64, 512 threads = 8 waves (4M x 2N), per-wave
// 64x128 = 4x8 16x16x32 frags (acc=128, A=32, br=32 regs -> 2 waves/SIMD).
// Per CU/step: MFMA 2480 cyc vs LDS reads ~1100 cyc -> MFMA-bound if overlapped.
template<int EPI>
__global__ __launch_bounds__(512, 2)
void conv_gemm9(const u16* __restrict__ Bsrc, const u16* __restrict__ Wq,
                const float* __restrict__ sptr, const float* __restrict__ bias,
                const float* __restrict__ resid, u16* __restrict__ outb,
                float* __restrict__ outf) {
    extern __shared__ u16 lds[];          // 131072 B (B-tiles in first 64KB)
    const int tid  = threadIdx.x;
    const int lane = tid & 63;
    const int wave = tid >> 6;
    const int wm = wave >> 1;             // 0..3  (M quarter, 64 rows)
    const int wn = wave & 1;              // 0..1  (N half, 128 cols)

    // T1: bijective XCD chunking (512 = 8 x 64); mt-pairs share a B-panel.
    const int wgid = (blockIdx.x & 7) * 64 + (blockIdx.x >> 3);
    const int mt = wgid & 1;
    const int nt = wgid >> 1;
    const int o0 = mt << 8;
    const int bb = nt >> 4;
    const int l0 = (nt & 15) << 8;

    // ---- B staging (R5-proven swizzle): 4 rounds of 64 rows x 64 cols ----
    const int sr  = tid >> 3;                              // 0..63
    const int scu = ((tid & 7) << 3) ^ ((sr & 7) << 3);    // pre-swizzled col
    const int sdst = tid << 3;
    const u16* bSrcBase = Bsrc + ((size_t)bb * LPAD + l0 + sr) * CCH + scu;

    auto stageB = [&](int pb, int ks2, int i02) {
        #pragma unroll
        for (int j = 0; j < 4; ++j)
            async16(bSrcBase + (size_t)(j * 64 + ks2) * CCH + i02,
                    &lds[pb * 16384 + j * 4096 + sdst]);
    };

    // ---- A direct-load base (per-lane invariant) ----
    const u16* aLane = Wq + ((size_t)(o0 + wm * 64 + (lane & 15)) << 9) +
                       ((lane >> 4) << 3);

    // ---- B read geometry (swizzled) ----
    const int swz = (lane & 7) << 3;
    const int c0 = ((lane >> 4) << 3) ^ swz;
    const int c1 = (((lane >> 4) << 3) + 32) ^ swz;
    const int bOffBase = (wn * 128 + (lane & 15)) * 64;    // + n*1024 + ck

    f32x4 acc[4][8];
    #pragma unroll
    for (int m = 0; m < 4; ++m)
        #pragma unroll
        for (int n = 0; n < 8; ++n)
            acc[m][n] = (f32x4){0.f, 0.f, 0.f, 0.f};

    // prologue: B tile 0 -> buf0
    stageB(0, 0, 0);
    WAIT_VM(0);
    HWBAR();

    int ks = 0, i0 = 0;
    for (int t = 0; t < 24; ++t) {
        const int pb = t & 1;
        // A fragments for THIS step: 8 x b128 from L2 (auto-waited on use)
        const u16* aT = aLane + ks * (CCH * CCH) + i0;
        bf16x8 aA[4][2];
        #pragma unroll
        for (int m = 0; m < 4; ++m) {
            aA[m][0] = *(const bf16x8*)(aT + m * 8192);
            aA[m][1] = *(const bf16x8*)(aT + m * 8192 + 32);
        }
        // next tile params (incremental, no div)
        int ksn = ks + 1, i0n = i0;
        if (ksn == 3) { ksn = 0; i0n += 64; }
        if (t < 23) stageB(pb ^ 1, ksn, i0n);      // prefetch next B tile
        const int cb = pb * 16384;
        #pragma unroll
        for (int kk = 0; kk < 2; ++kk) {
            const int ck = kk ? c1 : c0;
            bf16x8 br[8];
            #pragma unroll
            for (int n = 0; n < 8; ++n)
                br[n] = *(const bf16x8*)&lds[cb + bOffBase + n * 1024 + ck];
            __builtin_amdgcn_s_setprio(1);
            #pragma unroll
            for (int m = 0; m < 4; ++m)
                #pragma unroll
                for (int n = 0; n < 8; ++n)
                    acc[m][n] = __builtin_amdgcn_mfma_f32_16x16x32_bf16(
                        aA[m][kk], br[n], acc[m][n], 0, 0, 0);
            __builtin_amdgcn_s_setprio(0);
        }
        WAIT_LGKM0();                  // buf[pb] reads retired (WAR safety)
        WAIT_VM(0);                    // next B tile landed
        HWBAR();
        ks = ksn; i0 = i0n;
    }

    // epilogue
    const float sc = sptr[0];

    if (EPI == 1) {
        // silu(sc*acc+bias) -> LDS [l_loc 0..255][o_loc 0..255] bf16 swizzled
        // (row pitch 512B), then coalesced 16B stores.
        #pragma unroll
        for (int m = 0; m < 4; ++m) {
            const int o_loc = wm * 64 + m * 16 + ((lane >> 4) << 2);
            const int ob = o0 + o_loc;
            const float b0 = bias[ob + 0], b1 = bias[ob + 1];
            const float b2 = bias[ob + 2], b3 = bias[ob + 3];
            #pragma unroll
            for (int n = 0; n < 8; ++n) {
                const int l_loc = wn * 128 + n * 16 + (lane & 15);
                const f32x4 a = acc[m][n];
                u16x4 ov;
                ov[0] = f2bf(silu_f(sc * a[0] + b0));
                ov[1] = f2bf(silu_f(sc * a[1] + b1));
                ov[2] = f2bf(silu_f(sc * a[2] + b2));
                ov[3] = f2bf(silu_f(sc * a[3] + b3));
                char* p = (char*)lds + l_loc * 512 +
                          (((unsigned)(o_loc << 1)) ^ ((l_loc & 7) << 4));
                *(u16x4*)p = ov;
            }
        }
        __syncthreads();
        const int l_r = tid >> 2;            // 0..127
        const int oq  = (tid & 3) << 3;      // u16: 0,8,16,24
        #pragma unroll
        for (int pass = 0; pass < 2; ++pass) {
            const int lr = l_r + pass * 128;
            u16* gdst = outb + ((size_t)bb * LPAD + l0 + lr + 1) * CCH + o0 + oq;
            char* srp = (char*)lds + lr * 512;
            const int swz2 = (lr & 7) << 4;
            #pragma unroll
            for (int c = 0; c < 8; ++c) {
                const uint4 v = *(const uint4*)(srp + (((oq << 1) + c * 64) ^ swz2));
                *(uint4*)(gdst + c * 32) = v;
            }
        }
    } else {
        const int lbase = l0 + wn * 128 + (lane & 15);
        const int obase = o0 + wm * 64 + ((lane >> 4) << 2);
        #pragma unroll
        for (int m = 0; m < 4; ++m) {
            const int ob = obase + m * 16;
            #pragma unroll
            for (int n = 0; n < 8; ++n) {
                const int l = lbase + n * 16;
                const f32x4 a = acc[m][n];
                #pragma unroll
                for (int jj = 0; jj < 4; ++jj) {
                    const size_t idx = ((size_t)bb * CCH + (ob + jj)) * LEN + l;
                    outf[idx] = sc * a[jj] + bias[ob + jj] + resid[idx];
                }
            }
        }
    }
}

// ---------------------------------------------------------------------------
extern "C" void kernel_launch(void* const* d_in, const int* in_sizes, int n_in,
                              void* d_out, int out_size, void* d_ws, size_t ws_size,
                              hipStream_t stream) {
    const float* x  = (const float*)d_in[0];
    const float* w1 = (const float*)d_in[1];
    const float* b1 = (const float*)d_in[2];
    const float* w2 = (const float*)d_in[3];
    const float* b2 = (const float*)d_in[4];
    const float* g  = (const float*)d_in[5];
    float* out = (float*)d_out;

    char* ws = (char*)d_ws;
    float* sv   = (float*)ws;
    float* part = (float*)(ws + 256);
    u16* wq1   = (u16*)(ws + 4096);
    u16* wq2   = (u16*)(ws + 4096 + 1572864);
    u16* h_t   = (u16*)(ws + 4096 + 2 * 1572864);                 // [16][4098][512] bf16
    u16* h1_t  = (u16*)(ws + 4096 + 2 * 1572864 + 67141632);      // [16][4098][512] bf16

    hipFuncSetAttribute((const void*)conv_gemm9<1>,
                        hipFuncAttributeMaxDynamicSharedMemorySize, 131072);
    hipFuncSetAttribute((const void*)conv_gemm9<2>,
                        hipFuncAttributeMaxDynamicSharedMemorySize, 131072);

    absmean_partial<<<dim3(256), dim3(256), 0, stream>>>(w1, w2, part);
    finalize_scale<<<dim3(1), dim3(256), 0, stream>>>(part, sv);
    quantize_w<<<dim3(3072), dim3(256), 0, stream>>>(w1, sv, 0, wq1);
    quantize_w<<<dim3(3072), dim3(256), 0, stream>>>(w2, sv, 1, wq2);
    zero_pads<<<dim3(64), dim3(256), 0, stream>>>(h_t, h1_t);
    rms_silu_transpose<<<dim3(2048), dim3(256), 0, stream>>>(x, g, h_t);
    conv_gemm9<1><<<dim3(512), dim3(512), 131072, stream>>>(h_t, wq1, sv, b1,
                                                            nullptr, h1_t, nullptr);
    conv_gemm9<2><<<dim3(512), dim3(512), 131072, stream>>>(h1_t, wq2, sv + 1, b2,
                                                            x, nullptr, out);
}

// Round 10
// 332.684 us; speedup vs baseline: 1.3291x; 1.3291x over previous
//
#include <hip/hip_runtime.h>

#define BATCH 16
#define CCH 512
#define LEN 4096
#define LPAD 4098

typedef unsigned short u16;
typedef __bf16 bf16x8 __attribute__((ext_vector_type(8)));
typedef float f32x4 __attribute__((ext_vector_type(4)));
typedef float f32x16 __attribute__((ext_vector_type(16)));
typedef u16 u16x8 __attribute__((ext_vector_type(8)));
typedef u16 u16x4 __attribute__((ext_vector_type(4)));

__device__ __forceinline__ u16 f2bf(float f) {
    unsigned u = __float_as_uint(f);
    u = (u + 0x7fffu + ((u >> 16) & 1u)) >> 16;
    return (u16)u;
}
__device__ __forceinline__ float bf2f(u16 v) {
    return __uint_as_float(((unsigned)v) << 16);
}
__device__ __forceinline__ float silu_f(float v) {
    return v / (1.f + __expf(-v));
}
__device__ __forceinline__ void async16(const u16* g, u16* l) {
    __builtin_amdgcn_global_load_lds(
        (const __attribute__((address_space(1))) unsigned int*)g,
        (__attribute__((address_space(3))) unsigned int*)l, 16, 0, 0);
}

#define SBAR() __builtin_amdgcn_sched_barrier(0)
#define HWBAR() { SBAR(); __builtin_amdgcn_s_barrier(); SBAR(); }
#define WAIT_LGKM0() { asm volatile("s_waitcnt lgkmcnt(0)" ::: "memory"); SBAR(); }
#define WAIT_VM(n) { asm volatile("s_waitcnt vmcnt(" #n ")" ::: "memory"); SBAR(); }

// ---------------------------------------------------------------------------
__global__ __launch_bounds__(256)
void absmean_partial(const float* __restrict__ w1, const float* __restrict__ w2,
                     float* __restrict__ part) {
    const int tid = threadIdx.x;
    const int base = blockIdx.x * 3072;
    float s1 = 0.f, s2 = 0.f;
    for (int i = tid; i < 3072; i += 256) {
        s1 += fabsf(w1[base + i]);
        s2 += fabsf(w2[base + i]);
    }
    __shared__ float r1[256], r2[256];
    r1[tid] = s1; r2[tid] = s2;
    __syncthreads();
    for (int off = 128; off > 0; off >>= 1) {
        if (tid < off) { r1[tid] += r1[tid + off]; r2[tid] += r2[tid + off]; }
        __syncthreads();
    }
    if (tid == 0) { part[blockIdx.x] = r1[0]; part[256 + blockIdx.x] = r2[0]; }
}

__global__ __launch_bounds__(256)
void finalize_scale(const float* __restrict__ part, float* __restrict__ sv) {
    const int tid = threadIdx.x;
    __shared__ float r1[256], r2[256];
    r1[tid] = part[tid]; r2[tid] = part[256 + tid];
    __syncthreads();
    for (int off = 128; off > 0; off >>= 1) {
        if (tid < off) { r1[tid] += r1[tid + off]; r2[tid] += r2[tid + off]; }
        __syncthreads();
    }
    if (tid == 0) {
        sv[0] = fmaxf(r1[0] * (1.f / 786432.f), 1e-5f);
        sv[1] = fmaxf(r2[0] * (1.f / 786432.f), 1e-5f);
    }
}

// ---------------------------------------------------------------------------
// Quantize BOTH weight tensors: w[o][i][k] -> wq_t[k][o][i], ternary bf16.
__global__ __launch_bounds__(256)
void quantize_both(const float* __restrict__ w1, const float* __restrict__ w2,
                   const float* __restrict__ sv,
                   u16* __restrict__ wq1, u16* __restrict__ wq2) {
    const int idx = blockIdx.x * 256 + threadIdx.x;   // [0, 786432)
    const float s1 = sv[0], s2 = sv[1];
    const int o   = idx / 1536;
    const int rem = idx - o * 1536;
    const int i   = rem / 3;
    const int k   = rem - i * 3;
    const int dst = k * (CCH * CCH) + o * CCH + i;
    float q1 = fmaxf(-1.f, fminf(1.f, rintf(w1[idx] / s1)));
    float q2 = fmaxf(-1.f, fminf(1.f, rintf(w2[idx] / s2)));
    wq1[dst] = f2bf(q1);
    wq2[dst] = f2bf(q2);
}

__global__ __launch_bounds__(256)
void zero_pads(u16* __restrict__ h, u16* __restrict__ h1) {
    const int idx = blockIdx.x * 256 + threadIdx.x;   // [0, 16384)
    const int b = idx >> 10;
    const int r = (idx >> 9) & 1;
    const int i = idx & 511;
    const size_t off = ((size_t)b * LPAD + (r ? (LPAD - 1) : 0)) * CCH + i;
    h[off] = 0;
    h1[off] = 0;
}

// ---------------------------------------------------------------------------
__global__ __launch_bounds__(256)
void rms_silu_transpose(const float* __restrict__ x, const float* __restrict__ g,
                        u16* __restrict__ h_t) {
    __shared__ u16   xt[CCH][33];
    __shared__ float red[8][32];
    __shared__ float rinv[32];
    const int tid = threadIdx.x;
    const int bb  = blockIdx.x >> 7;
    const int l0  = (blockIdx.x & 127) << 5;

    const size_t xbase = (size_t)bb * CCH * LEN + l0;
    {
        const int i_hi = tid >> 3;
        const int l4   = (tid & 7) << 2;
        #pragma unroll
        for (int it = 0; it < 16; ++it) {
            const int i = it * 32 + i_hi;
            const float4 v = *(const float4*)&x[xbase + (size_t)i * LEN + l4];
            xt[i][l4 + 0] = f2bf(v.x);
            xt[i][l4 + 1] = f2bf(v.y);
            xt[i][l4 + 2] = f2bf(v.z);
            xt[i][l4 + 3] = f2bf(v.w);
        }
    }
    __syncthreads();
    {
        const int l = tid & 31, seg = tid >> 5;
        const int ibeg = seg * 64;
        float ss = 0.f;
        #pragma unroll 8
        for (int i = ibeg; i < ibeg + 64; ++i) {
            const float v = bf2f(xt[i][l]);
            ss += v * v;
        }
        red[seg][l] = ss;
    }
    __syncthreads();
    if (tid < 32) {
        float tot = 0.f;
        #pragma unroll
        for (int k2 = 0; k2 < 8; ++k2) tot += red[k2][tid];
        rinv[tid] = rsqrtf(tot * (1.f / 512.f) + 1e-6f);
    }
    __syncthreads();
    {
        const int l  = tid >> 3;
        const int i0 = (tid & 7) << 6;
        const float ri = rinv[l];
        const size_t ob = ((size_t)bb * LPAD + l0 + l + 1) * CCH + i0;
        for (int ii = 0; ii < 64; ii += 8) {
            u16x8 ov;
            #pragma unroll
            for (int jj = 0; jj < 8; ++jj) {
                const int i = i0 + ii + jj;
                float v = bf2f(xt[i][l]) * ri * g[i];
                ov[jj] = f2bf(silu_f(v));
            }
            *(u16x8*)&h_t[ob + ii] = ov;
        }
    }
}

// ---------------------------------------------------------------------------
// Conv-as-GEMM, R6 structure with 32x32x16 MFMA.
// 256x256 tile, 1024 threads = 16 waves (4M x 4N), per-wave 64x64 =
// 2x2 32x32 tiles, K=64 step = 4 k-slices of 16 -> 16 MFMA + 16 ds_read_b128
// per wave per step (halved MFMA instruction count vs 16x16x32).
// BK=64 double-buffered LDS 128 KiB, one barrier per K-step, T1+T2+T5.
template<int EPI>
__global__ __launch_bounds__(1024)
void conv_gemm10(const u16* __restrict__ Bsrc, const u16* __restrict__ Wq,
                 const float* __restrict__ sptr, const float* __restrict__ bias,
                 const float* __restrict__ resid, u16* __restrict__ outb,
                 float* __restrict__ outf) {
    extern __shared__ u16 lds[];          // 65536 u16 = 128 KiB
    const int tid  = threadIdx.x;
    const int lane = tid & 63;
    const int wave = tid >> 6;
    const int wm = wave >> 2;             // 0..3
    const int wn = wave & 3;              // 0..3

    // T1: bijective XCD chunking (512 = 8 x 64); mt-pairs share a B-panel.
    const int wgid = (blockIdx.x & 7) * 64 + (blockIdx.x >> 3);
    const int mt = wgid & 1;
    const int nt = wgid >> 1;
    const int o0 = mt << 8;
    const int bb = nt >> 4;
    const int l0 = (nt & 15) << 8;

    // staging (R6-proven): row = j*128 + (tid>>3), swizzled col
    const int sr  = tid >> 3;                              // 0..127
    const int scu = ((tid & 7) << 3) ^ ((sr & 7) << 3);    // pre-swizzled src col
    const int sdst = tid << 3;                             // u16 in 8192-u16 chunk

    const u16* aSrcBase = Wq + (size_t)o0 * CCH + scu;
    const u16* bSrcBase = Bsrc + ((size_t)bb * LPAD + l0) * CCH + scu;

    auto stage_full = [&](int pb, int ks2, int i02) {
        #pragma unroll
        for (int j = 0; j < 2; ++j) {
            const int r = j * 128 + sr;
            async16(aSrcBase + ks2 * (CCH * CCH) + r * CCH + i02,
                    &lds[pb * 32768 + j * 8192 + sdst]);
            async16(bSrcBase + (size_t)(r + ks2) * CCH + i02,
                    &lds[pb * 32768 + 16384 + j * 8192 + sdst]);
        }
    };

    // 32x32x16 read geometry: frag row = (lane&31), k = ks*16 + (lane>>5)*8.
    // swizzle: col ^ ((row&7)<<3); row&7 == lane&7 (tile bases are mult of 32).
    const int swz = (lane & 7) << 3;
    const int kb  = (lane >> 5) << 3;                      // 0 or 8
    const int aRowB = (wm * 64 + (lane & 31)) * 64;        // + mm*32*64
    const int bRowB = 16384 + (wn * 64 + (lane & 31)) * 64;

    f32x16 acc[2][2];
    #pragma unroll
    for (int m = 0; m < 2; ++m)
        #pragma unroll
        for (int n = 0; n < 2; ++n)
            acc[m][n] = (f32x16){0.f,0.f,0.f,0.f,0.f,0.f,0.f,0.f,
                                 0.f,0.f,0.f,0.f,0.f,0.f,0.f,0.f};

    stage_full(0, 0, 0);
    WAIT_VM(0);
    HWBAR();

    int ks = 0, i0 = 0;
    for (int t = 0; t < 24; ++t) {
        const int cur = t & 1;
        const int cbase = cur * 32768;
        int ksn = ks + 1, i0n = i0;
        if (ksn == 3) { ksn = 0; i0n += 64; }
        if (t < 23) stage_full(cur ^ 1, ksn, i0n);   // prefetch next tile
        #pragma unroll
        for (int s = 0; s < 4; ++s) {                // 4 k-slices of 16
            const int ck = (s * 16 + kb) ^ swz;
            bf16x8 av[2], bv[2];
            #pragma unroll
            for (int m = 0; m < 2; ++m)
                av[m] = *(const bf16x8*)&lds[cbase + aRowB + m * 2048 + ck];
            #pragma unroll
            for (int n = 0; n < 2; ++n)
                bv[n] = *(const bf16x8*)&lds[cbase + bRowB + n * 2048 + ck];
            __builtin_amdgcn_s_setprio(1);
            #pragma unroll
            for (int m = 0; m < 2; ++m)
                #pragma unroll
                for (int n = 0; n < 2; ++n)
                    acc[m][n] = __builtin_amdgcn_mfma_f32_32x32x16_bf16(
                        av[m], bv[n], acc[m][n], 0, 0, 0);
            __builtin_amdgcn_s_setprio(0);
        }
        WAIT_LGKM0();                  // reads of buf[cur] retired (WAR safety)
        WAIT_VM(0);                    // next tile landed
        HWBAR();
        ks = ksn; i0 = i0n;
    }

    // epilogue.  C/D 32x32 layout: col = lane&31, row = (r&3)+8*(r>>2)+4*hi.
    const float sc = sptr[0];
    const int hi = lane >> 5;

    if (EPI == 1) {
        #pragma unroll
        for (int m = 0; m < 2; ++m) {
            #pragma unroll
            for (int n = 0; n < 2; ++n) {
                const int l_loc = wn * 64 + n * 32 + (lane & 31);
                const f32x16 a = acc[m][n];
                #pragma unroll
                for (int q = 0; q < 4; ++q) {
                    const int o_loc = wm * 64 + m * 32 + q * 8 + hi * 4;
                    const int ob = o0 + o_loc;
                    u16x4 ov;
                    #pragma unroll
                    for (int j = 0; j < 4; ++j)
                        ov[j] = f2bf(silu_f(sc * a[q * 4 + j] + bias[ob + j]));
                    char* p = (char*)lds + l_loc * 512 +
                              (((unsigned)(o_loc << 1)) ^ ((l_loc & 7) << 4));
                    *(u16x4*)p = ov;
                }
            }
        }
        __syncthreads();
        const int l_r = tid >> 2;            // 0..255
        const int oq  = (tid & 3) << 3;      // u16: 0,8,16,24
        u16* gdst = outb + ((size_t)bb * LPAD + l0 + l_r + 1) * CCH + o0 + oq;
        char* srp = (char*)lds + l_r * 512;
        const int swz2 = (l_r & 7) << 4;
        #pragma unroll
        for (int c = 0; c < 8; ++c) {
            const uint4 v = *(const uint4*)(srp + (((oq << 1) + c * 64) ^ swz2));
            *(uint4*)(gdst + c * 32) = v;
        }
    } else {
        #pragma unroll
        for (int m = 0; m < 2; ++m) {
            #pragma unroll
            for (int n = 0; n < 2; ++n) {
                const int l = l0 + wn * 64 + n * 32 + (lane & 31);
                const f32x16 a = acc[m][n];
                #pragma unroll
                for (int q = 0; q < 4; ++q) {
                    const int ob = o0 + wm * 64 + m * 32 + q * 8 + hi * 4;
                    #pragma unroll
                    for (int j = 0; j < 4; ++j) {
                        const size_t idx = ((size_t)bb * CCH + (ob + j)) * LEN + l;
                        outf[idx] = sc * a[q * 4 + j] + bias[ob + j] + resid[idx];
                    }
                }
            }
        }
    }
}

// ---------------------------------------------------------------------------
extern "C" void kernel_launch(void* const* d_in, const int* in_sizes, int n_in,
                              void* d_out, int out_size, void* d_ws, size_t ws_size,
                              hipStream_t stream) {
    const float* x  = (const float*)d_in[0];
    const float* w1 = (const float*)d_in[1];
    const float* b1 = (const float*)d_in[2];
    const float* w2 = (const float*)d_in[3];
    const float* b2 = (const float*)d_in[4];
    const float* g  = (const float*)d_in[5];
    float* out = (float*)d_out;

    char* ws = (char*)d_ws;
    float* sv   = (float*)ws;
    float* part = (float*)(ws + 256);
    u16* wq1   = (u16*)(ws + 4096);
    u16* wq2   = (u16*)(ws + 4096 + 1572864);
    u16* h_t   = (u16*)(ws + 4096 + 2 * 1572864);                 // [16][4098][512] bf16
    u16* h1_t  = (u16*)(ws + 4096 + 2 * 1572864 + 67141632);      // [16][4098][512] bf16

    hipFuncSetAttribute((const void*)conv_gemm10<1>,
                        hipFuncAttributeMaxDynamicSharedMemorySize, 131072);
    hipFuncSetAttribute((const void*)conv_gemm10<2>,
                        hipFuncAttributeMaxDynamicSharedMemorySize, 131072);

    absmean_partial<<<dim3(256), dim3(256), 0, stream>>>(w1, w2, part);
    finalize_scale<<<dim3(1), dim3(256), 0, stream>>>(part, sv);
    quantize_both<<<dim3(3072), dim3(256), 0, stream>>>(w1, w2, sv, wq1, wq2);
    zero_pads<<<dim3(64), dim3(256), 0, stream>>>(h_t, h1_t);
    rms_silu_transpose<<<dim3(2048), dim3(256), 0, stream>>>(x, g, h_t);
    conv_gemm10<1><<<dim3(512), dim3(1024), 131072, stream>>>(h_t, wq1, sv, b1,
                                                              nullptr, h1_t, nullptr);
    conv_gemm10<2><<<dim3(512), dim3(1024), 131072, stream>>>(h1_t, wq2, sv + 1, b2,
                                                              x, nullptr, out);
}